// Round 7
// baseline (175.526 us; speedup 1.0000x reference)
//
#include <hip/hip_runtime.h>
#include <cstdint>
#include <cstddef>

typedef __bf16 bf16;
typedef __bf16 bf16x4 __attribute__((ext_vector_type(4)));
typedef __bf16 bf16x8 __attribute__((ext_vector_type(8)));
typedef float f32x4 __attribute__((ext_vector_type(4)));

#define DEVINL __device__ __forceinline__

static constexpr int Tn   = 1024;
static constexpr int DIM  = 1024;
static constexpr int NH   = 16;
static constexpr int DH   = 64;
static constexpr int QKVN = 3072;

DEVINL void g2l16(const void* g, void* l) {
  __builtin_amdgcn_global_load_lds(
      (const __attribute__((address_space(1))) void*)g,
      (__attribute__((address_space(3))) void*)l, 16, 0, 0);
}

// ---------------- pre/post utility kernels ----------------

// blocks [0,4096): f32->bf16 convert of x; blocks [4096,4160): fill the
// RoPE sin/cos table tab[t][i] = (cos, sin)(t * 10000^(-i/16)), 1024x16.
__global__ void k_convert_and_tab(const float* __restrict__ in, bf16* __restrict__ out,
                                  float2* __restrict__ tab) {
  if (blockIdx.x >= 4096) {
    int e = (blockIdx.x - 4096) * 256 + threadIdx.x;   // 0..16383
    int t = e >> 4, fi = e & 15;
    float inv = exp2f(-(float)fi * 0.830482023721841f);
    float sn, cs;
    sincosf((float)t * inv, &sn, &cs);
    tab[e] = make_float2(cs, sn);
    return;
  }
  int i = blockIdx.x * blockDim.x + threadIdx.x;
  float4 v = reinterpret_cast<const float4*>(in)[i];
  bf16 o[4] = {(bf16)v.x, (bf16)v.y, (bf16)v.z, (bf16)v.w};
  reinterpret_cast<uint2*>(out)[i] = *reinterpret_cast<uint2*>(o);
}

// W[K][N] f32 -> Wt[N][K] bf16   (block 32x8, grid (N/32, K/32))
__global__ void k_transpose_w(const float* __restrict__ in, bf16* __restrict__ out, int K, int N) {
  __shared__ float tile[32][33];
  int n0 = blockIdx.x * 32, k0 = blockIdx.y * 32;
  int tx = threadIdx.x, ty = threadIdx.y;
#pragma unroll
  for (int j = 0; j < 32; j += 8)
    tile[ty + j][tx] = in[(size_t)(k0 + ty + j) * N + n0 + tx];
  __syncthreads();
#pragma unroll
  for (int j = 0; j < 32; j += 8)
    out[(size_t)(n0 + ty + j) * K + k0 + tx] = (bf16)tile[tx][ty + j];
}

// V section of qkv -> vt[b][h][d][t]  (block 32x8, grid (T/32, DH/32, B*NH))
__global__ void k_transpose_v(const bf16* __restrict__ qkv, bf16* __restrict__ vt) {
  __shared__ bf16 tile[32][33];
  int t0 = blockIdx.x * 32, d0 = blockIdx.y * 32;
  int bh = blockIdx.z;
  int b = bh >> 4, h = bh & 15;
  int tx = threadIdx.x, ty = threadIdx.y;
#pragma unroll
  for (int j = 0; j < 32; j += 8)
    tile[ty + j][tx] = qkv[((size_t)(b * Tn + t0 + ty + j)) * QKVN + 2 * DIM + h * DH + d0 + tx];
  __syncthreads();
#pragma unroll
  for (int j = 0; j < 32; j += 8)
    vt[((size_t)(bh * DH + d0 + ty + j)) * Tn + t0 + tx] = tile[tx][ty + j];
}

// ---------------- MFMA GEMM: C[M,N] = A[M,K] * Bt[N,K]^T ----------------
// BM=128 fixed; BN = 128 (waves 2x2 of 64x64, NI=4) or 64 (waves 2x2 of 64x32, NI=2).
// ROPE: rotary epilogue via precomputed table (GEMM1 only; rotary iff
// col<2048 && (col&63)<32; pair partner col^1 lives in lane lrow^1 -> DPP shfl).
template <bool F32OUT, int BN, bool ROPE>
__global__ __launch_bounds__(256) void k_gemm_bt(
    const bf16* __restrict__ A, const bf16* __restrict__ Bt,
    void* __restrict__ Cp, const float2* __restrict__ tab, int M, int N, int K) {
  constexpr int NI = BN / 32;            // n-subtiles per wave
  __shared__ bf16 As[128 * 64];
  __shared__ bf16 Bs[BN * 64];
  const int tid  = threadIdx.x;
  const int wave = tid >> 6, lane = tid & 63;
  const int lrow = lane & 15, quad = lane >> 4;
  const int m0 = blockIdx.y * 128, n0 = blockIdx.x * BN;
  const int wm = (wave >> 1) * 64, wn = (wave & 1) * (BN / 2);

  f32x4 acc[4][NI];
#pragma unroll
  for (int mi = 0; mi < 4; mi++)
#pragma unroll
    for (int ni = 0; ni < NI; ni++) acc[mi][ni] = 0.f;

  for (int k0 = 0; k0 < K; k0 += 64) {
    __syncthreads();
#pragma unroll
    for (int i = 0; i < 4; i++) {
      int li = i * 256 + tid;
      int row = li >> 3, c = li & 7;
      int gc = c ^ (row & 7);
      g2l16(A + (size_t)(m0 + row) * K + k0 + gc * 8, As + li * 8);
    }
#pragma unroll
    for (int i = 0; i < BN / 32; i++) {
      int li = i * 256 + tid;
      int row = li >> 3, c = li & 7;
      int gc = c ^ (row & 7);
      g2l16(Bt + (size_t)(n0 + row) * K + k0 + gc * 8, Bs + li * 8);
    }
    __syncthreads();
#pragma unroll
    for (int ki = 0; ki < 2; ki++) {
      bf16x8 af[4], bfr[NI];
#pragma unroll
      for (int mi = 0; mi < 4; mi++) {
        int r = wm + mi * 16 + lrow;
        int pc = (ki * 4 + quad) ^ (r & 7);
        af[mi] = *reinterpret_cast<const bf16x8*>(As + r * 64 + pc * 8);
      }
#pragma unroll
      for (int ni = 0; ni < NI; ni++) {
        int r = wn + ni * 16 + lrow;
        int pc = (ki * 4 + quad) ^ (r & 7);
        bfr[ni] = *reinterpret_cast<const bf16x8*>(Bs + r * 64 + pc * 8);
      }
#pragma unroll
      for (int mi = 0; mi < 4; mi++)
#pragma unroll
        for (int ni = 0; ni < NI; ni++)
          acc[mi][ni] = __builtin_amdgcn_mfma_f32_16x16x32_bf16(af[mi], bfr[ni], acc[mi][ni], 0, 0, 0);
    }
  }

#pragma unroll
  for (int mi = 0; mi < 4; mi++)
#pragma unroll
    for (int ni = 0; ni < NI; ni++) {
      int col = n0 + wn + ni * 16 + lrow;
      bool rot = false;
      int fi = 0;
      if (ROPE) {
        rot = (col < 2 * DIM) && ((col & 63) < 32);   // wave-uniform per ni-tile
        fi = (col >> 1) & 15;
      }
#pragma unroll
      for (int r = 0; r < 4; r++) {
        int row = m0 + wm + mi * 16 + quad * 4 + r;
        float v = acc[mi][ni][r];
        if (ROPE) {
          float pv = __shfl_xor(v, 1, 64);            // partner col^1 (lane lrow^1)
          if (rot) {
            float2 cs = tab[((row & (Tn - 1)) << 4) + fi];
            v = (col & 1) ? (v * cs.x + pv * cs.y) : (v * cs.x - pv * cs.y);
          }
        }
        if (F32OUT)
          reinterpret_cast<float*>(Cp)[(size_t)row * N + col] = v;
        else
          reinterpret_cast<bf16*>(Cp)[(size_t)row * N + col] = (bf16)v;
      }
    }
}

// ---------------- causal flash attention ----------------
// Triangle-paired: block j handles q-tiles j and 15-j (uniform 17 compute units).
// grid (8, B*NH), 256 threads = 4 waves; each wave owns 16 q rows of EACH tile.
// Fixed-base softmax (exactly equivalent; |s|<~9 so exp2 can't overflow).
// Dual phase (kt<=jn): far+near processed TOGETHER — Ks/Vs fragments loaded
// once feed both MFMA chains; separate Ps regions (no LDS false dependency).
// Far-only phase (kt>jn): branch-free single chain.
__global__ __launch_bounds__(256) void k_attn(
    const bf16* __restrict__ qkv, const bf16* __restrict__ vt,
    bf16* __restrict__ ao) {
  __shared__ bf16 Ks[2][64 * 64];     // [key][d], 16B-chunk XOR swizzle by key&7
  __shared__ bf16 Vs[2][64 * 64];     // [d][key], chunk swizzle by d&7
  __shared__ bf16 Ps[8][16 * 64];     // [wave*2+set][q][key], chunk swizzle by q&7

  const int tid  = threadIdx.x;
  const int wave = tid >> 6, lane = tid & 63;
  const int lrow = lane & 15, quad = lane >> 4;
  const int bh = blockIdx.y, b = bh >> 4, h = bh & 15;
  const int jn = blockIdx.x;          // near q-tile (0..7)
  const int jf = 15 - jn;             // far q-tile (8..15)
  const int qwf = jf * 64 + wave * 16;
  const int qwn = jn * 64 + wave * 16;
  const size_t qbase = (size_t)b * Tn * QKVN;

  // Q fragments for both q-sets, pre-scaled by 1/sqrt(dh)*log2(e)
  bf16x8 qff[2], qfn[2];
  {
    const float SC = 0.125f * 1.44269504088896f;
    const bf16* qpf = qkv + qbase + (size_t)(qwf + lrow) * QKVN + h * DH;
    const bf16* qpn = qkv + qbase + (size_t)(qwn + lrow) * QKVN + h * DH;
    qff[0] = *reinterpret_cast<const bf16x8*>(qpf + quad * 8);
    qff[1] = *reinterpret_cast<const bf16x8*>(qpf + 32 + quad * 8);
    qfn[0] = *reinterpret_cast<const bf16x8*>(qpn + quad * 8);
    qfn[1] = *reinterpret_cast<const bf16x8*>(qpn + 32 + quad * 8);
#pragma unroll
    for (int j = 0; j < 8; j++) {
      qff[0][j] = (bf16)((float)qff[0][j] * SC);
      qff[1][j] = (bf16)((float)qff[1][j] * SC);
      qfn[0][j] = (bf16)((float)qfn[0][j] * SC);
      qfn[1][j] = (bf16)((float)qfn[1][j] * SC);
    }
  }

  f32x4 oaf[4], oan[4];
#pragma unroll
  for (int g = 0; g < 4; g++) { oaf[g] = 0.f; oan[g] = 0.f; }
  float lif = 0.f, lin = 0.f;
  const int qrel = wave * 16 + lrow;   // q within the 64-row q-tile

  const int ntiles = jf + 1;   // union of key tiles needed by both q-sets

  auto stage = [&](int k0, int bufi) {
#pragma unroll
    for (int i = 0; i < 2; i++) {
      int li2 = i * 256 + tid;
      int row = li2 >> 3, c = li2 & 7;
      int gc = c ^ (row & 7);
      g2l16(qkv + qbase + (size_t)(k0 + row) * QKVN + DIM + h * DH + gc * 8,
            &Ks[bufi][li2 * 8]);
      g2l16(vt + ((size_t)bh * DH + row) * Tn + k0 + gc * 8,
            &Vs[bufi][li2 * 8]);
    }
  };

  // exp + optional diagonal mask + packed store into Ps[pi]
  auto expstore = [&](f32x4 (&s)[4], float& li, int pi, bool diag) {
    float psum = 0.f;
#pragma unroll
    for (int g = 0; g < 4; g++) {
      bf16x4 pk;
#pragma unroll
      for (int r = 0; r < 4; r++) {
        float p = exp2f(s[g][r]);
        if (diag) {
          int kl = g * 16 + quad * 4 + r;   // key within tile
          p = (kl <= qrel) ? p : 0.f;
        }
        psum += p;
        pk[r] = (bf16)p;
      }
      int chunk = 2 * g + (quad >> 1);
      *reinterpret_cast<bf16x4*>(
          Ps[pi] + lrow * 64 + ((chunk ^ (lrow & 7)) << 3) + 4 * (quad & 1)) = pk;
    }
    li += psum;
  };

  stage(0, 0);

  // -------- dual phase: kt = 0..jn (far + near share Ks/Vs fragments) --------
  for (int kt = 0; kt <= jn; kt++) {
    const int buf = kt & 1;
    __syncthreads();
    if (kt + 1 < ntiles) stage((kt + 1) << 6, buf ^ 1);
    const bf16* ks = Ks[buf];
    const bf16* vs = Vs[buf];

    f32x4 sf[4], sn[4];
#pragma unroll
    for (int g = 0; g < 4; g++) { sf[g] = 0.f; sn[g] = 0.f; }
#pragma unroll
    for (int kh = 0; kh < 2; kh++) {
      const int cX = ((kh * 4 + quad) ^ (lrow & 7)) << 3;
#pragma unroll
      for (int g = 0; g < 4; g++) {
        bf16x8 kf = *reinterpret_cast<const bf16x8*>(ks + (g * 16 + lrow) * 64 + cX);
        sf[g] = __builtin_amdgcn_mfma_f32_16x16x32_bf16(kf, qff[kh], sf[g], 0, 0, 0);
        sn[g] = __builtin_amdgcn_mfma_f32_16x16x32_bf16(kf, qfn[kh], sn[g], 0, 0, 0);
      }
    }
    expstore(sf, lif, wave * 2 + 0, false);        // far diag is at kt==jf > jn
    expstore(sn, lin, wave * 2 + 1, kt == jn);
#pragma unroll
    for (int kh = 0; kh < 2; kh++) {
      const int cX = ((kh * 4 + quad) ^ (lrow & 7)) << 3;
      bf16x8 pff = *reinterpret_cast<const bf16x8*>(Ps[wave * 2 + 0] + lrow * 64 + cX);
      bf16x8 pfn = *reinterpret_cast<const bf16x8*>(Ps[wave * 2 + 1] + lrow * 64 + cX);
#pragma unroll
      for (int g = 0; g < 4; g++) {
        bf16x8 vf = *reinterpret_cast<const bf16x8*>(vs + (g * 16 + lrow) * 64 + cX);
        oaf[g] = __builtin_amdgcn_mfma_f32_16x16x32_bf16(pff, vf, oaf[g], 0, 0, 0);
        oan[g] = __builtin_amdgcn_mfma_f32_16x16x32_bf16(pfn, vf, oan[g], 0, 0, 0);
      }
    }
  }

  // -------- far-only phase: kt = jn+1..jf --------
  for (int kt = jn + 1; kt < ntiles; kt++) {
    const int buf = kt & 1;
    __syncthreads();
    if (kt + 1 < ntiles) stage((kt + 1) << 6, buf ^ 1);
    const bf16* ks = Ks[buf];
    const bf16* vs = Vs[buf];

    f32x4 sf[4];
#pragma unroll
    for (int g = 0; g < 4; g++) sf[g] = 0.f;
#pragma unroll
    for (int kh = 0; kh < 2; kh++) {
      const int cX = ((kh * 4 + quad) ^ (lrow & 7)) << 3;
#pragma unroll
      for (int g = 0; g < 4; g++) {
        bf16x8 kf = *reinterpret_cast<const bf16x8*>(ks + (g * 16 + lrow) * 64 + cX);
        sf[g] = __builtin_amdgcn_mfma_f32_16x16x32_bf16(kf, qff[kh], sf[g], 0, 0, 0);
      }
    }
    expstore(sf, lif, wave * 2 + 0, kt == jf);
#pragma unroll
    for (int kh = 0; kh < 2; kh++) {
      const int cX = ((kh * 4 + quad) ^ (lrow & 7)) << 3;
      bf16x8 pff = *reinterpret_cast<const bf16x8*>(Ps[wave * 2 + 0] + lrow * 64 + cX);
#pragma unroll
      for (int g = 0; g < 4; g++) {
        bf16x8 vf = *reinterpret_cast<const bf16x8*>(vs + (g * 16 + lrow) * 64 + cX);
        oaf[g] = __builtin_amdgcn_mfma_f32_16x16x32_bf16(pff, vf, oaf[g], 0, 0, 0);
      }
    }
  }

  // denominators: in-lane partials -> reduce across quads, then distribute per row
  lif += __shfl_xor(lif, 16, 64); lif += __shfl_xor(lif, 32, 64);
  lin += __shfl_xor(lin, 16, 64); lin += __shfl_xor(lin, 32, 64);

#pragma unroll
  for (int r = 0; r < 4; r++) {
    int m = quad * 4 + r;
    float invf = 1.0f / __shfl(lif, m, 64);
    float invn = 1.0f / __shfl(lin, m, 64);
    bf16* dstf = ao + ((size_t)b * Tn + qwf + m) * DIM + h * DH;
    bf16* dstn = ao + ((size_t)b * Tn + qwn + m) * DIM + h * DH;
    dstf[ 0 + lrow] = (bf16)(oaf[0][r] * invf);
    dstf[16 + lrow] = (bf16)(oaf[1][r] * invf);
    dstf[32 + lrow] = (bf16)(oaf[2][r] * invf);
    dstf[48 + lrow] = (bf16)(oaf[3][r] * invf);
    dstn[ 0 + lrow] = (bf16)(oan[0][r] * invn);
    dstn[16 + lrow] = (bf16)(oan[1][r] * invn);
    dstn[32 + lrow] = (bf16)(oan[2][r] * invn);
    dstn[48 + lrow] = (bf16)(oan[3][r] * invn);
  }
}

// ---------------- launcher ----------------
extern "C" void kernel_launch(void* const* d_in, const int* in_sizes, int n_in,
                              void* d_out, int out_size, void* d_ws, size_t ws_size,
                              hipStream_t stream) {
  const float* x    = (const float*)d_in[0];
  const float* Wqkv = (const float*)d_in[1];
  const float* Wout = (const float*)d_in[2];
  char* ws = (char*)d_ws;

  bf16*   xb    = (bf16*)(ws + 0);
  bf16*   wqkvT = (bf16*)(ws + 8388608);
  bf16*   woutT = (bf16*)(ws + 14680064);
  bf16*   qkv   = (bf16*)(ws + 16777216);
  bf16*   vt    = (bf16*)(ws + 41943040);
  bf16*   ao    = (bf16*)(ws + 50331648);
  float2* tab   = (float2*)(ws + 58720256);   // 128 KiB sin/cos table

  k_convert_and_tab<<<4160, 256, 0, stream>>>(x, xb, tab);
  k_transpose_w<<<dim3(96, 32), dim3(32, 8), 0, stream>>>(Wqkv, wqkvT, 1024, 3072);
  k_transpose_w<<<dim3(32, 32), dim3(32, 8), 0, stream>>>(Wout, woutT, 1024, 1024);
  // GEMM1 with fused RoPE epilogue (table-driven)
  k_gemm_bt<false, 128, true><<<dim3(24, 32), 256, 0, stream>>>(
      xb, wqkvT, (void*)qkv, tab, 4096, 3072, 1024);
  k_transpose_v<<<dim3(32, 2, 64), dim3(32, 8), 0, stream>>>(qkv, vt);
  k_attn<<<dim3(8, 64), 256, 0, stream>>>(qkv, vt, ao);
  // GEMM2: BN=64 -> 512 blocks (2+/CU)
  k_gemm_bt<true, 64, false><<<dim3(16, 32), 256, 0, stream>>>(
      ao, woutT, d_out, nullptr, 4096, 1024, 1024);
  (void)in_sizes; (void)n_in; (void)out_size; (void)ws_size;
}

// Round 8
// 173.681 us; speedup vs baseline: 1.0106x; 1.0106x over previous
//
#include <hip/hip_runtime.h>
#include <cstdint>
#include <cstddef>

typedef __bf16 bf16;
typedef __bf16 bf16x4 __attribute__((ext_vector_type(4)));
typedef __bf16 bf16x8 __attribute__((ext_vector_type(8)));
typedef float f32x4 __attribute__((ext_vector_type(4)));

#define DEVINL __device__ __forceinline__

static constexpr int Tn   = 1024;
static constexpr int DIM  = 1024;
static constexpr int NH   = 16;
static constexpr int DH   = 64;
static constexpr int QKVN = 3072;

DEVINL void g2l16(const void* g, void* l) {
  __builtin_amdgcn_global_load_lds(
      (const __attribute__((address_space(1))) void*)g,
      (__attribute__((address_space(3))) void*)l, 16, 0, 0);
}

// ---------------- pre/post utility kernels ----------------

// blocks [0,4096): f32->bf16 convert of x; blocks [4096,4160): fill the
// RoPE sin/cos table tab[t][i] = (cos, sin)(t * 10000^(-i/16)), 1024x16.
__global__ void k_convert_and_tab(const float* __restrict__ in, bf16* __restrict__ out,
                                  float2* __restrict__ tab) {
  if (blockIdx.x >= 4096) {
    int e = (blockIdx.x - 4096) * 256 + threadIdx.x;   // 0..16383
    int t = e >> 4, fi = e & 15;
    float inv = exp2f(-(float)fi * 0.830482023721841f);
    float sn, cs;
    sincosf((float)t * inv, &sn, &cs);
    tab[e] = make_float2(cs, sn);
    return;
  }
  int i = blockIdx.x * blockDim.x + threadIdx.x;
  float4 v = reinterpret_cast<const float4*>(in)[i];
  bf16 o[4] = {(bf16)v.x, (bf16)v.y, (bf16)v.z, (bf16)v.w};
  reinterpret_cast<uint2*>(out)[i] = *reinterpret_cast<uint2*>(o);
}

// Both weight transposes in one launch. blocks x<96: Wqkv (1024x3072);
// x>=96: Wout (1024x1024). W[K][N] f32 -> Wt[N][K] bf16.
__global__ void k_transpose_w2(const float* __restrict__ w1, bf16* __restrict__ o1,
                               const float* __restrict__ w2, bf16* __restrict__ o2) {
  __shared__ float tile[32][33];
  const bool second = blockIdx.x >= 96;
  const float* in = second ? w2 : w1;
  bf16* out = second ? o2 : o1;
  const int N = second ? 1024 : 3072;
  int n0 = (second ? (blockIdx.x - 96) : blockIdx.x) * 32, k0 = blockIdx.y * 32;
  int tx = threadIdx.x, ty = threadIdx.y;
#pragma unroll
  for (int j = 0; j < 32; j += 8)
    tile[ty + j][tx] = in[(size_t)(k0 + ty + j) * N + n0 + tx];
  __syncthreads();
#pragma unroll
  for (int j = 0; j < 32; j += 8)
    out[(size_t)(n0 + ty + j) * 1024 + k0 + tx] = (bf16)tile[tx][ty + j];
}

// ---------------- MFMA GEMM: C[M,N] = A[M,K] * Bt[N,K]^T ----------------
// BM=128 fixed; BN = 128 (waves 2x2 of 64x64, NI=4) or 64 (waves 2x2 of 64x32, NI=2).
// QKV variant (ROPE=true): rotary epilogue via table for q,k sections
// (col<2048 && (col&63)<32); V section (col>=2048) is written TRANSPOSED
// directly into vt[b*1024+hd][t] (4 consecutive t per lane -> bf16x4 store).
template <bool F32OUT, int BN, bool ROPE>
__global__ __launch_bounds__(256) void k_gemm_bt(
    const bf16* __restrict__ A, const bf16* __restrict__ Bt,
    void* __restrict__ Cp, bf16* __restrict__ vt, const float2* __restrict__ tab,
    int M, int N, int K) {
  constexpr int NI = BN / 32;            // n-subtiles per wave
  __shared__ bf16 As[128 * 64];
  __shared__ bf16 Bs[BN * 64];
  const int tid  = threadIdx.x;
  const int wave = tid >> 6, lane = tid & 63;
  const int lrow = lane & 15, quad = lane >> 4;
  const int m0 = blockIdx.y * 128, n0 = blockIdx.x * BN;
  const int wm = (wave >> 1) * 64, wn = (wave & 1) * (BN / 2);

  f32x4 acc[4][NI];
#pragma unroll
  for (int mi = 0; mi < 4; mi++)
#pragma unroll
    for (int ni = 0; ni < NI; ni++) acc[mi][ni] = 0.f;

  for (int k0 = 0; k0 < K; k0 += 64) {
    __syncthreads();
#pragma unroll
    for (int i = 0; i < 4; i++) {
      int li = i * 256 + tid;
      int row = li >> 3, c = li & 7;
      int gc = c ^ (row & 7);
      g2l16(A + (size_t)(m0 + row) * K + k0 + gc * 8, As + li * 8);
    }
#pragma unroll
    for (int i = 0; i < BN / 32; i++) {
      int li = i * 256 + tid;
      int row = li >> 3, c = li & 7;
      int gc = c ^ (row & 7);
      g2l16(Bt + (size_t)(n0 + row) * K + k0 + gc * 8, Bs + li * 8);
    }
    __syncthreads();
#pragma unroll
    for (int ki = 0; ki < 2; ki++) {
      bf16x8 af[4], bfr[NI];
#pragma unroll
      for (int mi = 0; mi < 4; mi++) {
        int r = wm + mi * 16 + lrow;
        int pc = (ki * 4 + quad) ^ (r & 7);
        af[mi] = *reinterpret_cast<const bf16x8*>(As + r * 64 + pc * 8);
      }
#pragma unroll
      for (int ni = 0; ni < NI; ni++) {
        int r = wn + ni * 16 + lrow;
        int pc = (ki * 4 + quad) ^ (r & 7);
        bfr[ni] = *reinterpret_cast<const bf16x8*>(Bs + r * 64 + pc * 8);
      }
#pragma unroll
      for (int mi = 0; mi < 4; mi++)
#pragma unroll
        for (int ni = 0; ni < NI; ni++)
          acc[mi][ni] = __builtin_amdgcn_mfma_f32_16x16x32_bf16(af[mi], bfr[ni], acc[mi][ni], 0, 0, 0);
    }
  }

#pragma unroll
  for (int mi = 0; mi < 4; mi++)
#pragma unroll
    for (int ni = 0; ni < NI; ni++) {
      int col = n0 + wn + ni * 16 + lrow;
      if (ROPE && col >= 2 * DIM) {
        // V section: write transposed into vt (4 consecutive t per lane)
        int hd = col - 2 * DIM;                        // h*64 + d
        int row0 = m0 + wm + mi * 16 + quad * 4;       // same batch for all 4 rows
        bf16x4 pk;
#pragma unroll
        for (int r = 0; r < 4; r++) pk[r] = (bf16)acc[mi][ni][r];
        *reinterpret_cast<bf16x4*>(
            vt + ((size_t)(((row0 >> 10) << 10) + hd) << 10) + (row0 & (Tn - 1))) = pk;
        continue;
      }
      bool rot = false;
      int fi = 0;
      if (ROPE) {
        rot = (col & 63) < 32;                         // wave-uniform per ni-tile
        fi = (col >> 1) & 15;
      }
#pragma unroll
      for (int r = 0; r < 4; r++) {
        int row = m0 + wm + mi * 16 + quad * 4 + r;
        float v = acc[mi][ni][r];
        if (ROPE && rot) {
          float pv = __shfl_xor(v, 1, 64);             // partner col^1 (lane lrow^1)
          float2 cs = tab[((row & (Tn - 1)) << 4) + fi];
          v = (col & 1) ? (v * cs.x + pv * cs.y) : (v * cs.x - pv * cs.y);
        }
        if (F32OUT)
          reinterpret_cast<float*>(Cp)[(size_t)row * N + col] = v;
        else
          reinterpret_cast<bf16*>(Cp)[(size_t)row * N + col] = (bf16)v;
      }
    }
}

// ---------------- causal flash attention (R6-best form) ----------------
// Triangle-paired: block j handles q-tiles j and 15-j (uniform 17 compute units).
// grid (8, B*NH), 256 threads = 4 waves; each wave owns 16 q rows of EACH tile.
// Fixed-base softmax (exactly equivalent; |s|<~9 so exp2 can't overflow).
// S^T via swapped MFMA operands -> packed ds_write_b64 P stores, in-lane denom.
// Sequential far/near units sharing one per-wave Ps region (measured best: R6).
__global__ __launch_bounds__(256) void k_attn(
    const bf16* __restrict__ qkv, const bf16* __restrict__ vt,
    bf16* __restrict__ ao) {
  __shared__ bf16 Ks[2][64 * 64];     // [key][d], 16B-chunk XOR swizzle by key&7
  __shared__ bf16 Vs[2][64 * 64];     // [d][key], chunk swizzle by d&7
  __shared__ bf16 Ps[4][16 * 64];     // per-wave P (reused by both q-sets)

  const int tid  = threadIdx.x;
  const int wave = tid >> 6, lane = tid & 63;
  const int lrow = lane & 15, quad = lane >> 4;
  const int bh = blockIdx.y, b = bh >> 4, h = bh & 15;
  const int jn = blockIdx.x;          // near q-tile (0..7)
  const int jf = 15 - jn;             // far q-tile (8..15)
  const int qwf = jf * 64 + wave * 16;
  const int qwn = jn * 64 + wave * 16;
  const size_t qbase = (size_t)b * Tn * QKVN;

  // Q fragments for both q-sets, pre-scaled by 1/sqrt(dh)*log2(e)
  bf16x8 qff[2], qfn[2];
  {
    const float SC = 0.125f * 1.44269504088896f;
    const bf16* qpf = qkv + qbase + (size_t)(qwf + lrow) * QKVN + h * DH;
    const bf16* qpn = qkv + qbase + (size_t)(qwn + lrow) * QKVN + h * DH;
    qff[0] = *reinterpret_cast<const bf16x8*>(qpf + quad * 8);
    qff[1] = *reinterpret_cast<const bf16x8*>(qpf + 32 + quad * 8);
    qfn[0] = *reinterpret_cast<const bf16x8*>(qpn + quad * 8);
    qfn[1] = *reinterpret_cast<const bf16x8*>(qpn + 32 + quad * 8);
#pragma unroll
    for (int j = 0; j < 8; j++) {
      qff[0][j] = (bf16)((float)qff[0][j] * SC);
      qff[1][j] = (bf16)((float)qff[1][j] * SC);
      qfn[0][j] = (bf16)((float)qfn[0][j] * SC);
      qfn[1][j] = (bf16)((float)qfn[1][j] * SC);
    }
  }

  f32x4 oaf[4], oan[4];
#pragma unroll
  for (int g = 0; g < 4; g++) { oaf[g] = 0.f; oan[g] = 0.f; }
  float lif = 0.f, lin = 0.f;

  const int ntiles = jf + 1;   // union of key tiles needed by both q-sets

  auto stage = [&](int k0, int bufi) {
#pragma unroll
    for (int i = 0; i < 2; i++) {
      int li2 = i * 256 + tid;
      int row = li2 >> 3, c = li2 & 7;
      int gc = c ^ (row & 7);
      g2l16(qkv + qbase + (size_t)(k0 + row) * QKVN + DIM + h * DH + gc * 8,
            &Ks[bufi][li2 * 8]);
      g2l16(vt + ((size_t)bh * DH + row) * Tn + k0 + gc * 8,
            &Vs[bufi][li2 * 8]);
    }
  };

  // one 64-key tile for one q-set: S^T = K Q^T, exp, packed P store, O += P V
  auto unit = [&](const bf16* ks, const bf16* vs, bf16x8 (&qf)[2], f32x4 (&oa)[4],
                  float& li, bool diag) {
    f32x4 s[4];
#pragma unroll
    for (int g = 0; g < 4; g++) s[g] = 0.f;
#pragma unroll
    for (int kh = 0; kh < 2; kh++) {
      const int cX = ((kh * 4 + quad) ^ (lrow & 7)) << 3;
#pragma unroll
      for (int g = 0; g < 4; g++) {
        bf16x8 kf = *reinterpret_cast<const bf16x8*>(ks + (g * 16 + lrow) * 64 + cX);
        s[g] = __builtin_amdgcn_mfma_f32_16x16x32_bf16(kf, qf[kh], s[g], 0, 0, 0);
      }
    }
    // lane holds S^T[key = 16g+4*quad+r][q = wave*16 + lrow]
    float psum = 0.f;
    const int qrel = wave * 16 + lrow;   // q within the 64-row q-tile
#pragma unroll
    for (int g = 0; g < 4; g++) {
      bf16x4 pk;
#pragma unroll
      for (int r = 0; r < 4; r++) {
        float p = exp2f(s[g][r]);
        if (diag) {
          int kl = g * 16 + quad * 4 + r;   // key within tile
          p = (kl <= qrel) ? p : 0.f;
        }
        psum += p;
        pk[r] = (bf16)p;
      }
      int chunk = 2 * g + (quad >> 1);
      *reinterpret_cast<bf16x4*>(
          Ps[wave] + lrow * 64 + ((chunk ^ (lrow & 7)) << 3) + 4 * (quad & 1)) = pk;
    }
    li += psum;
#pragma unroll
    for (int kh = 0; kh < 2; kh++) {
      const int cX = ((kh * 4 + quad) ^ (lrow & 7)) << 3;
      bf16x8 pf = *reinterpret_cast<const bf16x8*>(Ps[wave] + lrow * 64 + cX);
#pragma unroll
      for (int g = 0; g < 4; g++) {
        bf16x8 vf = *reinterpret_cast<const bf16x8*>(vs + (g * 16 + lrow) * 64 + cX);
        oa[g] = __builtin_amdgcn_mfma_f32_16x16x32_bf16(pf, vf, oa[g], 0, 0, 0);
      }
    }
  };

  stage(0, 0);

  for (int kt = 0; kt < ntiles; kt++) {
    const int buf = kt & 1;
    __syncthreads();                                   // tile kt resident
    if (kt + 1 < ntiles) stage((kt + 1) << 6, buf ^ 1);  // overlaps compute

    const bf16* ks = Ks[buf];
    const bf16* vs = Vs[buf];

    unit(ks, vs, qff, oaf, lif, kt == jf);   // far tile: always active
    if (kt <= jn)
      unit(ks, vs, qfn, oan, lin, kt == jn); // near tile
  }

  // denominators: in-lane partials -> reduce across quads, then distribute per row
  lif += __shfl_xor(lif, 16, 64); lif += __shfl_xor(lif, 32, 64);
  lin += __shfl_xor(lin, 16, 64); lin += __shfl_xor(lin, 32, 64);

#pragma unroll
  for (int r = 0; r < 4; r++) {
    int m = quad * 4 + r;
    float invf = 1.0f / __shfl(lif, m, 64);
    float invn = 1.0f / __shfl(lin, m, 64);
    bf16* dstf = ao + ((size_t)b * Tn + qwf + m) * DIM + h * DH;
    bf16* dstn = ao + ((size_t)b * Tn + qwn + m) * DIM + h * DH;
    dstf[ 0 + lrow] = (bf16)(oaf[0][r] * invf);
    dstf[16 + lrow] = (bf16)(oaf[1][r] * invf);
    dstf[32 + lrow] = (bf16)(oaf[2][r] * invf);
    dstf[48 + lrow] = (bf16)(oaf[3][r] * invf);
    dstn[ 0 + lrow] = (bf16)(oan[0][r] * invn);
    dstn[16 + lrow] = (bf16)(oan[1][r] * invn);
    dstn[32 + lrow] = (bf16)(oan[2][r] * invn);
    dstn[48 + lrow] = (bf16)(oan[3][r] * invn);
  }
}

// ---------------- launcher ----------------
extern "C" void kernel_launch(void* const* d_in, const int* in_sizes, int n_in,
                              void* d_out, int out_size, void* d_ws, size_t ws_size,
                              hipStream_t stream) {
  const float* x    = (const float*)d_in[0];
  const float* Wqkv = (const float*)d_in[1];
  const float* Wout = (const float*)d_in[2];
  char* ws = (char*)d_ws;

  bf16*   xb    = (bf16*)(ws + 0);
  bf16*   wqkvT = (bf16*)(ws + 8388608);
  bf16*   woutT = (bf16*)(ws + 14680064);
  bf16*   qkv   = (bf16*)(ws + 16777216);
  bf16*   vt    = (bf16*)(ws + 41943040);
  bf16*   ao    = (bf16*)(ws + 50331648);
  float2* tab   = (float2*)(ws + 58720256);   // 128 KiB sin/cos table

  k_convert_and_tab<<<4160, 256, 0, stream>>>(x, xb, tab);
  k_transpose_w2<<<dim3(128, 32), dim3(32, 8), 0, stream>>>(Wqkv, wqkvT, Wout, woutT);
  // GEMM1: fused RoPE epilogue (q,k) + direct transposed V write into vt
  k_gemm_bt<false, 128, true><<<dim3(24, 32), 256, 0, stream>>>(
      xb, wqkvT, (void*)qkv, vt, tab, 4096, 3072, 1024);
  k_attn<<<dim3(8, 64), 256, 0, stream>>>(qkv, vt, ao);
  // GEMM2: BN=64 -> 512 blocks (2+/CU)
  k_gemm_bt<true, 64, false><<<dim3(16, 32), 256, 0, stream>>>(
      ao, woutT, d_out, nullptr, nullptr, 4096, 1024, 1024);
  (void)in_sizes; (void)n_in; (void)out_size; (void)ws_size;
}

// Round 9
// 160.686 us; speedup vs baseline: 1.0924x; 1.0809x over previous
//
#include <hip/hip_runtime.h>
#include <cstdint>
#include <cstddef>

typedef __bf16 bf16;
typedef __bf16 bf16x4 __attribute__((ext_vector_type(4)));
typedef __bf16 bf16x8 __attribute__((ext_vector_type(8)));
typedef float f32x4 __attribute__((ext_vector_type(4)));

#define DEVINL __device__ __forceinline__

static constexpr int Tn   = 1024;
static constexpr int DIM  = 1024;
static constexpr int NH   = 16;
static constexpr int DH   = 64;
static constexpr int QKVN = 3072;

DEVINL void g2l16(const void* g, void* l) {
  __builtin_amdgcn_global_load_lds(
      (const __attribute__((address_space(1))) void*)g,
      (__attribute__((address_space(3))) void*)l, 16, 0, 0);
}

// ---------------- fused prep: x convert + rope table + both W transposes ----
// blocks [0,4096): f32->bf16 convert of x (float4/lane)
// blocks [4096,4160): tab[t][i] = (cos,sin)(t * 10000^(-i/16)), 1024x16
// blocks [4160,7232): Wqkv transpose (1024x3072 -> 3072x1024 bf16)
// blocks [7232,8256): Wout transpose (1024x1024 -> 1024x1024 bf16)
__global__ void k_prep(const float* __restrict__ x, bf16* __restrict__ xb,
                       float2* __restrict__ tab,
                       const float* __restrict__ w1, bf16* __restrict__ o1,
                       const float* __restrict__ w2, bf16* __restrict__ o2) {
  __shared__ float tile[32][33];
  int bx = blockIdx.x;
  if (bx < 4096) {
    int i = bx * 256 + threadIdx.x;
    float4 v = reinterpret_cast<const float4*>(x)[i];
    bf16 o[4] = {(bf16)v.x, (bf16)v.y, (bf16)v.z, (bf16)v.w};
    reinterpret_cast<uint2*>(xb)[i] = *reinterpret_cast<uint2*>(o);
    return;
  }
  if (bx < 4160) {
    int e = (bx - 4096) * 256 + threadIdx.x;   // 0..16383
    int t = e >> 4, fi = e & 15;
    float inv = exp2f(-(float)fi * 0.830482023721841f);
    float sn, cs;
    sincosf((float)t * inv, &sn, &cs);
    tab[e] = make_float2(cs, sn);
    return;
  }
  int sub = bx - 4160;
  const float* in; bf16* out; int N, n0, k0;
  if (sub < 3072) { in = w1; out = o1; N = 3072; n0 = (sub % 96) * 32; k0 = (sub / 96) * 32; }
  else { sub -= 3072; in = w2; out = o2; N = 1024; n0 = (sub & 31) * 32; k0 = (sub >> 5) * 32; }
  int tx = threadIdx.x & 31, ty = threadIdx.x >> 5;
#pragma unroll
  for (int j = 0; j < 32; j += 8)
    tile[ty + j][tx] = in[(size_t)(k0 + ty + j) * N + n0 + tx];
  __syncthreads();
#pragma unroll
  for (int j = 0; j < 32; j += 8)
    out[(size_t)(n0 + ty + j) * 1024 + k0 + tx] = (bf16)tile[tx][ty + j];
}

// ---------------- MFMA GEMM (swapped-operand): C[M,N] = A[M,K] * Bt[N,K]^T --
// mfma(B-frag, A-frag): lane holds D[n = base_n + quad*4 + r][m = base_m + lrow]
// -> 4 CONSECUTIVE output columns per lane: in-register RoPE (no shfl),
// vectorized bf16x4/float4 stores.
// ROPE (GEMM1): q/k blocks (n0<2048): rotary on (col&63)<32 subtiles via table;
// V blocks (n0>=2048, block-uniform): write transposed into vt[b*1024+hd][t].
template <bool F32OUT, int BN, bool ROPE>
__global__ __launch_bounds__(256) void k_gemm_bt(
    const bf16* __restrict__ A, const bf16* __restrict__ Bt,
    void* __restrict__ Cp, bf16* __restrict__ vt, const float2* __restrict__ tab,
    int M, int N, int K) {
  constexpr int NI = BN / 32;            // n-subtiles per wave
  constexpr int NB = BN / 32;            // B staging chunks
  __shared__ bf16 As[128 * 64];
  __shared__ bf16 Bs[BN * 64];
  const int tid  = threadIdx.x;
  const int wave = tid >> 6, lane = tid & 63;
  const int lrow = lane & 15, quad = lane >> 4;
  const int m0 = blockIdx.y * 128, n0 = blockIdx.x * BN;
  const int wm = (wave >> 1) * 64, wn = (wave & 1) * (BN / 2);

  // hoisted staging pointers (advance by 64 each k-iter)
  const bf16* aP[4];
  const bf16* bP[NB];
#pragma unroll
  for (int i = 0; i < 4; i++) {
    int li = i * 256 + tid;
    int row = li >> 3, c = li & 7, gc = c ^ (row & 7);
    aP[i] = A + (size_t)(m0 + row) * K + gc * 8;
  }
#pragma unroll
  for (int i = 0; i < NB; i++) {
    int li = i * 256 + tid;
    int row = li >> 3, c = li & 7, gc = c ^ (row & 7);
    bP[i] = Bt + (size_t)(n0 + row) * K + gc * 8;
  }

  f32x4 acc[4][NI];
#pragma unroll
  for (int mi = 0; mi < 4; mi++)
#pragma unroll
    for (int ni = 0; ni < NI; ni++) acc[mi][ni] = 0.f;

  for (int k0 = 0; k0 < K; k0 += 64) {
    __syncthreads();
#pragma unroll
    for (int i = 0; i < 4; i++) {
      g2l16(aP[i], As + (i * 256 + tid) * 8);
      aP[i] += 64;
    }
#pragma unroll
    for (int i = 0; i < NB; i++) {
      g2l16(bP[i], Bs + (i * 256 + tid) * 8);
      bP[i] += 64;
    }
    __syncthreads();
#pragma unroll
    for (int ki = 0; ki < 2; ki++) {
      bf16x8 af[4], bfr[NI];
#pragma unroll
      for (int mi = 0; mi < 4; mi++) {
        int r = wm + mi * 16 + lrow;
        int pc = (ki * 4 + quad) ^ (r & 7);
        af[mi] = *reinterpret_cast<const bf16x8*>(As + r * 64 + pc * 8);
      }
#pragma unroll
      for (int ni = 0; ni < NI; ni++) {
        int r = wn + ni * 16 + lrow;
        int pc = (ki * 4 + quad) ^ (r & 7);
        bfr[ni] = *reinterpret_cast<const bf16x8*>(Bs + r * 64 + pc * 8);
      }
#pragma unroll
      for (int mi = 0; mi < 4; mi++)
#pragma unroll
        for (int ni = 0; ni < NI; ni++)
          acc[mi][ni] = __builtin_amdgcn_mfma_f32_16x16x32_bf16(bfr[ni], af[mi], acc[mi][ni], 0, 0, 0);
    }
  }

  // epilogue: lane owns row (m0+wm+mi*16+lrow), cols colb..colb+3
#pragma unroll
  for (int mi = 0; mi < 4; mi++) {
    const int row = m0 + wm + mi * 16 + lrow;
#pragma unroll
    for (int ni = 0; ni < NI; ni++) {
      const int colb = n0 + wn + ni * 16 + quad * 4;
      f32x4 v = acc[mi][ni];
      if (ROPE && n0 >= 2 * DIM) {
        // V section (block-uniform): vt[(b<<10) + hd][t], 2B x 16 contiguous t
        int t = row & (Tn - 1), bb = row >> 10;
        int hdb = colb - 2 * DIM;
#pragma unroll
        for (int r = 0; r < 4; r++)
          vt[((size_t)((bb << 10) + hdb + r) << 10) + t] = (bf16)v[r];
        continue;
      }
      if (ROPE && ((colb & 63) < 32)) {
        int t = row & (Tn - 1);
        int fi0 = (colb >> 1) & 15;         // even; pairs (r0,r1)=fi0, (r2,r3)=fi0+1
        float2 c0 = tab[(t << 4) + fi0];
        float2 c1 = tab[(t << 4) + fi0 + 1];
        float a0 = v[0], a1 = v[1], a2 = v[2], a3 = v[3];
        v[0] = a0 * c0.x - a1 * c0.y;
        v[1] = a1 * c0.x + a0 * c0.y;
        v[2] = a2 * c1.x - a3 * c1.y;
        v[3] = a3 * c1.x + a2 * c1.y;
      }
      if (F32OUT) {
        float4 st = {v[0], v[1], v[2], v[3]};
        *reinterpret_cast<float4*>(reinterpret_cast<float*>(Cp) + (size_t)row * N + colb) = st;
      } else {
        bf16x4 pk;
#pragma unroll
        for (int r = 0; r < 4; r++) pk[r] = (bf16)v[r];
        *reinterpret_cast<bf16x4*>(reinterpret_cast<bf16*>(Cp) + (size_t)row * N + colb) = pk;
      }
    }
  }
}

// ---------------- causal flash attention (R6-best form) ----------------
// Triangle-paired: block j handles q-tiles j and 15-j (uniform 17 compute units).
// grid (8, B*NH), 256 threads = 4 waves; each wave owns 16 q rows of EACH tile.
// Fixed-base softmax (exactly equivalent; |s|<~9 so exp2 can't overflow).
// S^T via swapped MFMA operands -> packed ds_write_b64 P stores, in-lane denom.
__global__ __launch_bounds__(256) void k_attn(
    const bf16* __restrict__ qkv, const bf16* __restrict__ vt,
    bf16* __restrict__ ao) {
  __shared__ bf16 Ks[2][64 * 64];     // [key][d], 16B-chunk XOR swizzle by key&7
  __shared__ bf16 Vs[2][64 * 64];     // [d][key], chunk swizzle by d&7
  __shared__ bf16 Ps[4][16 * 64];     // per-wave P (reused by both q-sets)

  const int tid  = threadIdx.x;
  const int wave = tid >> 6, lane = tid & 63;
  const int lrow = lane & 15, quad = lane >> 4;
  const int bh = blockIdx.y, b = bh >> 4, h = bh & 15;
  const int jn = blockIdx.x;          // near q-tile (0..7)
  const int jf = 15 - jn;             // far q-tile (8..15)
  const int qwf = jf * 64 + wave * 16;
  const int qwn = jn * 64 + wave * 16;
  const size_t qbase = (size_t)b * Tn * QKVN;

  // Q fragments for both q-sets, pre-scaled by 1/sqrt(dh)*log2(e)
  bf16x8 qff[2], qfn[2];
  {
    const float SC = 0.125f * 1.44269504088896f;
    const bf16* qpf = qkv + qbase + (size_t)(qwf + lrow) * QKVN + h * DH;
    const bf16* qpn = qkv + qbase + (size_t)(qwn + lrow) * QKVN + h * DH;
    qff[0] = *reinterpret_cast<const bf16x8*>(qpf + quad * 8);
    qff[1] = *reinterpret_cast<const bf16x8*>(qpf + 32 + quad * 8);
    qfn[0] = *reinterpret_cast<const bf16x8*>(qpn + quad * 8);
    qfn[1] = *reinterpret_cast<const bf16x8*>(qpn + 32 + quad * 8);
#pragma unroll
    for (int j = 0; j < 8; j++) {
      qff[0][j] = (bf16)((float)qff[0][j] * SC);
      qff[1][j] = (bf16)((float)qff[1][j] * SC);
      qfn[0][j] = (bf16)((float)qfn[0][j] * SC);
      qfn[1][j] = (bf16)((float)qfn[1][j] * SC);
    }
  }

  f32x4 oaf[4], oan[4];
#pragma unroll
  for (int g = 0; g < 4; g++) { oaf[g] = 0.f; oan[g] = 0.f; }
  float lif = 0.f, lin = 0.f;

  const int ntiles = jf + 1;   // union of key tiles needed by both q-sets

  auto stage = [&](int k0, int bufi) {
#pragma unroll
    for (int i = 0; i < 2; i++) {
      int li2 = i * 256 + tid;
      int row = li2 >> 3, c = li2 & 7;
      int gc = c ^ (row & 7);
      g2l16(qkv + qbase + (size_t)(k0 + row) * QKVN + DIM + h * DH + gc * 8,
            &Ks[bufi][li2 * 8]);
      g2l16(vt + ((size_t)bh * DH + row) * Tn + k0 + gc * 8,
            &Vs[bufi][li2 * 8]);
    }
  };

  // one 64-key tile for one q-set: S^T = K Q^T, exp, packed P store, O += P V
  auto unit = [&](const bf16* ks, const bf16* vs, bf16x8 (&qf)[2], f32x4 (&oa)[4],
                  float& li, bool diag) {
    f32x4 s[4];
#pragma unroll
    for (int g = 0; g < 4; g++) s[g] = 0.f;
#pragma unroll
    for (int kh = 0; kh < 2; kh++) {
      const int cX = ((kh * 4 + quad) ^ (lrow & 7)) << 3;
#pragma unroll
      for (int g = 0; g < 4; g++) {
        bf16x8 kf = *reinterpret_cast<const bf16x8*>(ks + (g * 16 + lrow) * 64 + cX);
        s[g] = __builtin_amdgcn_mfma_f32_16x16x32_bf16(kf, qf[kh], s[g], 0, 0, 0);
      }
    }
    // lane holds S^T[key = 16g+4*quad+r][q = wave*16 + lrow]
    float psum = 0.f;
    const int qrel = wave * 16 + lrow;   // q within the 64-row q-tile
#pragma unroll
    for (int g = 0; g < 4; g++) {
      bf16x4 pk;
#pragma unroll
      for (int r = 0; r < 4; r++) {
        float p = exp2f(s[g][r]);
        if (diag) {
          int kl = g * 16 + quad * 4 + r;   // key within tile
          p = (kl <= qrel) ? p : 0.f;
        }
        psum += p;
        pk[r] = (bf16)p;
      }
      int chunk = 2 * g + (quad >> 1);
      *reinterpret_cast<bf16x4*>(
          Ps[wave] + lrow * 64 + ((chunk ^ (lrow & 7)) << 3) + 4 * (quad & 1)) = pk;
    }
    li += psum;
#pragma unroll
    for (int kh = 0; kh < 2; kh++) {
      const int cX = ((kh * 4 + quad) ^ (lrow & 7)) << 3;
      bf16x8 pf = *reinterpret_cast<const bf16x8*>(Ps[wave] + lrow * 64 + cX);
#pragma unroll
      for (int g = 0; g < 4; g++) {
        bf16x8 vf = *reinterpret_cast<const bf16x8*>(vs + (g * 16 + lrow) * 64 + cX);
        oa[g] = __builtin_amdgcn_mfma_f32_16x16x32_bf16(pf, vf, oa[g], 0, 0, 0);
      }
    }
  };

  stage(0, 0);

  for (int kt = 0; kt < ntiles; kt++) {
    const int buf = kt & 1;
    __syncthreads();                                   // tile kt resident
    if (kt + 1 < ntiles) stage((kt + 1) << 6, buf ^ 1);  // overlaps compute

    const bf16* ks = Ks[buf];
    const bf16* vs = Vs[buf];

    unit(ks, vs, qff, oaf, lif, kt == jf);   // far tile: always active
    if (kt <= jn)
      unit(ks, vs, qfn, oan, lin, kt == jn); // near tile
  }

  // denominators: in-lane partials -> reduce across quads, then distribute per row
  lif += __shfl_xor(lif, 16, 64); lif += __shfl_xor(lif, 32, 64);
  lin += __shfl_xor(lin, 16, 64); lin += __shfl_xor(lin, 32, 64);

#pragma unroll
  for (int r = 0; r < 4; r++) {
    int m = quad * 4 + r;
    float invf = 1.0f / __shfl(lif, m, 64);
    float invn = 1.0f / __shfl(lin, m, 64);
    bf16* dstf = ao + ((size_t)b * Tn + qwf + m) * DIM + h * DH;
    bf16* dstn = ao + ((size_t)b * Tn + qwn + m) * DIM + h * DH;
    dstf[ 0 + lrow] = (bf16)(oaf[0][r] * invf);
    dstf[16 + lrow] = (bf16)(oaf[1][r] * invf);
    dstf[32 + lrow] = (bf16)(oaf[2][r] * invf);
    dstf[48 + lrow] = (bf16)(oaf[3][r] * invf);
    dstn[ 0 + lrow] = (bf16)(oan[0][r] * invn);
    dstn[16 + lrow] = (bf16)(oan[1][r] * invn);
    dstn[32 + lrow] = (bf16)(oan[2][r] * invn);
    dstn[48 + lrow] = (bf16)(oan[3][r] * invn);
  }
}

// ---------------- launcher ----------------
extern "C" void kernel_launch(void* const* d_in, const int* in_sizes, int n_in,
                              void* d_out, int out_size, void* d_ws, size_t ws_size,
                              hipStream_t stream) {
  const float* x    = (const float*)d_in[0];
  const float* Wqkv = (const float*)d_in[1];
  const float* Wout = (const float*)d_in[2];
  char* ws = (char*)d_ws;

  bf16*   xb    = (bf16*)(ws + 0);
  bf16*   wqkvT = (bf16*)(ws + 8388608);
  bf16*   woutT = (bf16*)(ws + 14680064);
  bf16*   qkv   = (bf16*)(ws + 16777216);
  bf16*   vt    = (bf16*)(ws + 41943040);
  bf16*   ao    = (bf16*)(ws + 50331648);
  float2* tab   = (float2*)(ws + 58720256);   // 128 KiB sin/cos table

  k_prep<<<8256, 256, 0, stream>>>(x, xb, tab, Wqkv, wqkvT, Wout, woutT);
  // GEMM1: fused RoPE epilogue (in-register pairs) + direct transposed V write
  k_gemm_bt<false, 128, true><<<dim3(24, 32), 256, 0, stream>>>(
      xb, wqkvT, (void*)qkv, vt, tab, 4096, 3072, 1024);
  k_attn<<<dim3(8, 64), 256, 0, stream>>>(qkv, vt, ao);
  // GEMM2: BN=64 -> 512 blocks (2+/CU)
  k_gemm_bt<true, 64, false><<<dim3(16, 32), 256, 0, stream>>>(
      ao, woutT, d_out, nullptr, nullptr, 4096, 1024, 1024);
  (void)in_sizes; (void)n_in; (void)out_size; (void)ws_size;
}